// Round 1
// baseline (243.293 us; speedup 1.0000x reference)
//
#include <hip/hip_runtime.h>
#include <limits.h>

#define HB 16
#define HH 96
#define HW 96
#define HN (HH*HW)
// sentinel for "column has no mask pixel": must exceed max real d^2 (95^2+95^2=18050)
// and fit in ushort with headroom: 24576 + 9025 < 65535 and < INT_MAX when summed.
#define SENT 24576

// ---------------- Kernel 1: per-column 1-D squared distance transform ----------------
// One thread per (img, x) column. Builds 96-bit masks for pred/target columns,
// then for each y finds nearest set bit (expected O(1) at 50% density).
__global__ void col_pass(const float* __restrict__ pred,
                         const float* __restrict__ targ,
                         unsigned short* __restrict__ gA2,
                         unsigned short* __restrict__ gB2) {
    int gid = blockIdx.x * blockDim.x + threadIdx.x;
    if (gid >= HB * HW) return;
    int img = gid / HW;
    int x   = gid - img * HW;
    const float* p = pred + img * HN + x;
    const float* t = targ + img * HN + x;

    unsigned mA[3] = {0u, 0u, 0u}, mB[3] = {0u, 0u, 0u};
    for (int y = 0; y < HH; ++y) {
        float pv = p[y * HW];
        float tv = t[y * HW];
        if (pv >= 0.5f) mA[y >> 5] |= (1u << (y & 31));
        if (tv >= 0.5f) mB[y >> 5] |= (1u << (y & 31));
    }

    int base = img * HN + x;
    for (int y = 0; y < HH; ++y) {
        int dA = HH, dB = HH;
        for (int d = 0; d < HH; ++d) {
            int lo = y - d, hi = y + d;
            bool f = (lo >= 0 && ((mA[lo >> 5] >> (lo & 31)) & 1u)) ||
                     (hi < HH && ((mA[hi >> 5] >> (hi & 31)) & 1u));
            if (f) { dA = d; break; }
        }
        for (int d = 0; d < HH; ++d) {
            int lo = y - d, hi = y + d;
            bool f = (lo >= 0 && ((mB[lo >> 5] >> (lo & 31)) & 1u)) ||
                     (hi < HH && ((mB[hi >> 5] >> (hi & 31)) & 1u));
            if (f) { dB = d; break; }
        }
        gA2[base + y * HW] = (unsigned short)((dA < HH) ? dA * dA : SENT);
        gB2[base + y * HW] = (unsigned short)((dB < HH) ? dB * dB : SENT);
    }
}

// ---------------- Kernel 2: per-row combine + per-image max-reduce ----------------
// Block = 192 threads = 2 rows of one image. dt2(y,x) = min_x' g2(y,x') + (x-x')^2.
// candAB = a ? dt2_to_B : -1; per-image accumulators seeded to -1 so "any(A)" is
// (maxAB2 >= 0).
__global__ __launch_bounds__(192) void row_pass(const float* __restrict__ pred,
                                                const float* __restrict__ targ,
                                                const unsigned short* __restrict__ gA2,
                                                const unsigned short* __restrict__ gB2,
                                                int* __restrict__ maxAB2,
                                                int* __restrict__ maxBA2) {
    int blk = blockIdx.x;                 // 0 .. HB*HH/2 - 1
    int img = blk / (HH / 2);
    int y0  = (blk - img * (HH / 2)) * 2;
    int tid = threadIdx.x;                // 0..191
    int s   = tid / HW;                   // sub-row 0/1
    int x   = tid - s * HW;

    __shared__ int sA[2 * HW], sB[2 * HW];
    __shared__ int redAB, redBA;

    int base = img * HN + y0 * HW;        // two contiguous rows
    sA[tid] = (int)gA2[base + tid];
    sB[tid] = (int)gB2[base + tid];
    if (tid == 0) { redAB = -1; redBA = -1; }
    __syncthreads();

    const int* rA = sA + s * HW;
    const int* rB = sB + s * HW;
    int dA2 = INT_MAX, dB2 = INT_MAX;
    #pragma unroll 4
    for (int xp = 0; xp < HW; ++xp) {
        int dx = x - xp;
        int w  = dx * dx;
        dA2 = min(dA2, rA[xp] + w);
        dB2 = min(dB2, rB[xp] + w);
    }

    int idx = base + tid;
    bool a = pred[idx] >= 0.5f;
    bool b = targ[idx] >= 0.5f;
    int candAB = a ? dB2 : -1;            // distance from A-point to set B
    int candBA = b ? dA2 : -1;            // distance from B-point to set A
    atomicMax(&redAB, candAB);
    atomicMax(&redBA, candBA);
    __syncthreads();
    if (tid == 0) {
        atomicMax(&maxAB2[img], redAB);
        atomicMax(&maxBA2[img], redBA);
    }
}

// ---------------- Kernel 3: finalize (empty-set rules + mean) ----------------
__global__ void finalize(const float* __restrict__ pred,
                         const float* __restrict__ targ,
                         const int* __restrict__ maxAB2,
                         const int* __restrict__ maxBA2,
                         float* __restrict__ out) {
    __shared__ float hd[HB];
    __shared__ int diam2;
    int tid = threadIdx.x;

    if (tid < HB) {
        int mAB = maxAB2[tid], mBA = maxBA2[tid];
        bool anyA = mAB >= 0, anyB = mBA >= 0;
        float v;
        if (anyA && anyB)      v = sqrtf((float)max(mAB, mBA));
        else if (!anyA && !anyB) v = 0.0f;
        else                   v = -1.0f;   // needs diameter fallback
        hd[tid] = v;
    }
    __syncthreads();

    // Fallback: one set empty -> diameter of the other. Dead code for these
    // inputs (50%-dense random masks are never empty), kept for correctness.
    for (int img = 0; img < HB; ++img) {
        if (hd[img] >= 0.0f) continue;     // block-uniform condition
        bool anyA = maxAB2[img] >= 0;
        const float* src = anyA ? pred : targ;
        if (tid == 0) diam2 = 0;
        __syncthreads();
        int local = 0;
        for (int i = tid; i < HN; i += blockDim.x) {
            if (src[img * HN + i] >= 0.5f) {
                int yi = i / HW, xi = i - (i / HW) * HW;
                for (int j = 0; j < HN; ++j) {
                    if (src[img * HN + j] >= 0.5f) {
                        int yj = j / HW, xj = j - (j / HW) * HW;
                        int dy = yi - yj, dx = xi - xj;
                        local = max(local, dy * dy + dx * dx);
                    }
                }
            }
        }
        atomicMax(&diam2, local);
        __syncthreads();
        if (tid == 0) hd[img] = sqrtf((float)diam2);
        __syncthreads();
    }

    if (tid == 0) {
        float sum = 0.0f;
        for (int i = 0; i < HB; ++i) sum += hd[i];
        out[0] = sum * (1.0f / HB);
    }
}

extern "C" void kernel_launch(void* const* d_in, const int* in_sizes, int n_in,
                              void* d_out, int out_size, void* d_ws, size_t ws_size,
                              hipStream_t stream) {
    const float* pred = (const float*)d_in[0];
    const float* targ = (const float*)d_in[1];
    float* out = (float*)d_out;

    // workspace layout: gA2 (ushort[B*N]), gB2 (ushort[B*N]), maxAB2[int HB], maxBA2[int HB]
    unsigned short* gA2 = (unsigned short*)d_ws;
    unsigned short* gB2 = gA2 + HB * HN;
    int* maxAB2 = (int*)(gB2 + HB * HN);
    int* maxBA2 = maxAB2 + HB;

    // seed per-image max accumulators to -1 (0xFFFFFFFF)
    hipMemsetAsync(maxAB2, 0xFF, 2 * HB * sizeof(int), stream);

    col_pass<<<(HB * HW + 255) / 256, 256, 0, stream>>>(pred, targ, gA2, gB2);
    row_pass<<<HB * HH / 2, 192, 0, stream>>>(pred, targ, gA2, gB2, maxAB2, maxBA2);
    finalize<<<1, 256, 0, stream>>>(pred, targ, maxAB2, maxBA2, out);
}

// Round 2
// 71.504 us; speedup vs baseline: 3.4025x; 3.4025x over previous
//
#include <hip/hip_runtime.h>
#include <limits.h>

#define HB 16
#define HH 96
#define HW 96
#define HN (HH*HW)
#define WPR 3              // u32 words per mask row
#define WPI (HH*WPR)       // 288 words per image mask
#define STRIPES 12
#define ROWS_PER (HH/STRIPES)   // 8
#define PX_PER (ROWS_PER*HW)    // 768

// ---------------- Kernel 1: build 96-bit row masks via wave ballot ----------------
// One thread per pixel, fully coalesced loads. A 64-lane ballot covers 64
// consecutive flat pixels; since HW=96=3*32, flat 32-bit words align to rows.
__global__ __launch_bounds__(256) void mask_build(const float* __restrict__ pred,
                                                  const float* __restrict__ targ,
                                                  unsigned int* __restrict__ mA,
                                                  unsigned int* __restrict__ mB) {
    int i = blockIdx.x * 256 + threadIdx.x;          // flat over all images
    float pv = pred[i], tv = targ[i];
    unsigned long long balA = __ballot(pv >= 0.5f);
    unsigned long long balB = __ballot(tv >= 0.5f);
    if ((threadIdx.x & 63) == 0) {
        int img = i / HN;
        int f = i - img * HN;
        int w = img * WPI + (f >> 5);
        mA[w]   = (unsigned int)balA;
        mA[w+1] = (unsigned int)(balA >> 32);
        mB[w]   = (unsigned int)balB;
        mB[w+1] = (unsigned int)(balB >> 32);
    }
}

// nearest |x - x'| over set bits of a 96-bit row (lo = bits 0..63, hi = 64..95).
// Row must be non-empty; result <= 95.
__device__ __forceinline__ int nearest_dx(unsigned long long lo, unsigned int hi, int x) {
    int dr = 1 << 20, dl = 1 << 20;
    if (x < 64) {
        unsigned long long r = lo >> x;
        if (r) dr = __builtin_ctzll(r);
        else if (hi) dr = (64 - x) + __builtin_ctz(hi);
        unsigned long long lm = lo << (63 - x);      // bit x -> bit 63
        if (lm) dl = __builtin_clzll(lm);
    } else {
        int xh = x - 64;                             // 0..31
        unsigned int r = hi >> xh;
        if (r) dr = __builtin_ctz(r);
        unsigned int lmh = hi << (31 - xh);          // bit xh -> bit 31
        if (lmh) dl = __builtin_clz(lmh);
        else if (lo) dl = (xh + 1) + __builtin_clzll(lo);
    }
    return min(dl, dr);
}

// squared distance from (y,x) to nearest set pixel in mask m (96 rows x 3 words).
// Returns INT_MAX if the set is empty. Expanding-ring search: break when dy^2 >= best.
__device__ __forceinline__ int search2d(const unsigned int* __restrict__ m, int y, int x) {
    int best = INT_MAX;
    for (int dy = 0; dy < HH; ++dy) {
        if (dy * dy >= best) break;
        int yl = y - dy;
        if (yl >= 0) {
            unsigned long long lo = (unsigned long long)m[yl*WPR] |
                                    ((unsigned long long)m[yl*WPR+1] << 32);
            unsigned int hi = m[yl*WPR+2];
            if (lo | hi) {
                int dx = nearest_dx(lo, hi, x);
                best = min(best, dy*dy + dx*dx);
            }
        }
        int yh = y + dy;
        if (dy > 0 && yh < HH) {
            unsigned long long lo = (unsigned long long)m[yh*WPR] |
                                    ((unsigned long long)m[yh*WPR+1] << 32);
            unsigned int hi = m[yh*WPR+2];
            if (lo | hi) {
                int dx = nearest_dx(lo, hi, x);
                best = min(best, dy*dy + dx*dx);
            }
        }
    }
    return best;
}

// ---------------- Kernel 2: per-pixel directed distances + per-image max ----------------
__global__ __launch_bounds__(256) void search_pass(const unsigned int* __restrict__ mA,
                                                   const unsigned int* __restrict__ mB,
                                                   int* __restrict__ maxAB2,
                                                   int* __restrict__ maxBA2) {
    int img    = blockIdx.x / STRIPES;
    int stripe = blockIdx.x - img * STRIPES;
    int tid = threadIdx.x;
    __shared__ unsigned int sA[WPI], sB[WPI];
    __shared__ int redAB, redBA;
    for (int w = tid; w < WPI; w += 256) {
        sA[w] = mA[img*WPI + w];
        sB[w] = mB[img*WPI + w];
    }
    if (tid == 0) { redAB = -1; redBA = -1; }
    __syncthreads();

    int lAB = -1, lBA = -1;
    #pragma unroll
    for (int k = 0; k < PX_PER; k += 256) {
        int li = k + tid;
        int ry = li / HW;
        int y  = stripe * ROWS_PER + ry;
        int x  = li - ry * HW;
        bool a = (sA[y*WPR + (x>>5)] >> (x & 31)) & 1u;
        bool b = (sB[y*WPR + (x>>5)] >> (x & 31)) & 1u;
        if (a) lAB = max(lAB, search2d(sB, y, x));   // A-point -> set B
        if (b) lBA = max(lBA, search2d(sA, y, x));   // B-point -> set A
    }
    atomicMax(&redAB, lAB);
    atomicMax(&redBA, lBA);
    __syncthreads();
    if (tid == 0) {
        atomicMax(&maxAB2[img], redAB);
        atomicMax(&maxBA2[img], redBA);
    }
}

// ---------------- Kernel 3: finalize (empty-set rules + mean) ----------------
__global__ void finalize(const float* __restrict__ pred,
                         const float* __restrict__ targ,
                         const int* __restrict__ maxAB2,
                         const int* __restrict__ maxBA2,
                         float* __restrict__ out) {
    __shared__ float hd[HB];
    __shared__ int diam2;
    int tid = threadIdx.x;

    if (tid < HB) {
        int mAB = maxAB2[tid], mBA = maxBA2[tid];
        bool anyA = mAB >= 0, anyB = mBA >= 0;
        float v;
        if (anyA && anyB)        v = sqrtf((float)max(mAB, mBA));
        else if (!anyA && !anyB) v = 0.0f;
        else                     v = -1.0f;   // needs diameter fallback
        hd[tid] = v;
    }
    __syncthreads();

    // Fallback: one set empty -> diameter of the other. Dead for these inputs
    // (50%-dense random masks are never empty); kept for correctness.
    for (int img = 0; img < HB; ++img) {
        if (hd[img] >= 0.0f) continue;        // block-uniform condition
        bool anyA = maxAB2[img] >= 0;
        const float* src = anyA ? pred : targ;
        if (tid == 0) diam2 = 0;
        __syncthreads();
        int local = 0;
        for (int i = tid; i < HN; i += blockDim.x) {
            if (src[img * HN + i] >= 0.5f) {
                int yi = i / HW, xi = i - (i / HW) * HW;
                for (int j = 0; j < HN; ++j) {
                    if (src[img * HN + j] >= 0.5f) {
                        int yj = j / HW, xj = j - (j / HW) * HW;
                        int dy = yi - yj, dx = xi - xj;
                        local = max(local, dy * dy + dx * dx);
                    }
                }
            }
        }
        atomicMax(&diam2, local);
        __syncthreads();
        if (tid == 0) hd[img] = sqrtf((float)diam2);
        __syncthreads();
    }

    if (tid == 0) {
        float sum = 0.0f;
        for (int i = 0; i < HB; ++i) sum += hd[i];
        out[0] = sum * (1.0f / HB);
    }
}

extern "C" void kernel_launch(void* const* d_in, const int* in_sizes, int n_in,
                              void* d_out, int out_size, void* d_ws, size_t ws_size,
                              hipStream_t stream) {
    const float* pred = (const float*)d_in[0];
    const float* targ = (const float*)d_in[1];
    float* out = (float*)d_out;

    // ws layout: mA u32[HB*WPI], mB u32[HB*WPI], maxAB2 int[HB], maxBA2 int[HB]
    unsigned int* mA = (unsigned int*)d_ws;
    unsigned int* mB = mA + HB * WPI;
    int* maxAB2 = (int*)(mB + HB * WPI);
    int* maxBA2 = maxAB2 + HB;

    hipMemsetAsync(maxAB2, 0xFF, 2 * HB * sizeof(int), stream);  // seed to -1

    mask_build<<<HB * HN / 256, 256, 0, stream>>>(pred, targ, mA, mB);
    search_pass<<<HB * STRIPES, 256, 0, stream>>>(mA, mB, maxAB2, maxBA2);
    finalize<<<1, 256, 0, stream>>>(pred, targ, maxAB2, maxBA2, out);
}